// Round 13
// baseline (707.170 us; speedup 1.0000x reference)
//
#include <hip/hip_runtime.h>
#include <hip/hip_bf16.h>
#include <cstdint>
#include <cstddef>

typedef __hip_bfloat16 bf16;
typedef short bf16x8 __attribute__((ext_vector_type(8)));
typedef float f32x4 __attribute__((ext_vector_type(4)));

#define MFMA(a, b, c) __builtin_amdgcn_mfma_f32_16x16x32_bf16((a), (b), (c), 0, 0, 0)

// ===========================================================================
// Device bodies, shared by all dispatch modes of pipe_k.
// Buffers (qwM, KS, VT) are indexed by (wid - bufoff); SK slot = batch&skmask.
// ===========================================================================

__device__ __forceinline__ void d_wtrans(int idx, const float* wq,
                                         const float* wkv, const float* wp,
                                         bf16* wqT, bf16* wkvT, bf16* wpT) {
  if (idx < 65536) {
    int n = idx >> 8, k = idx & 255;
    wqT[idx] = __float2bfloat16(wq[k * 256 + n]);
  } else if (idx < 196608) {
    int i = idx - 65536;
    int n = i >> 8, k = i & 255;
    wkvT[i] = __float2bfloat16(wkv[k * 512 + n]);
  } else {
    int i = idx - 196608;
    int n = i >> 8, k = i & 255;
    wpT[i] = __float2bfloat16(wp[k * 256 + n]);
  }
}

__device__ __forceinline__ void d_stageq(int tile, int tid, const float* src,
                                         bf16* qwM, int swoff, char* SMEM) {
  bf16(*T)[66] = (bf16(*)[66])SMEM;
  int c0 = (tile & 3) << 6;
  int hwb = (tile >> 2) << 6;
  {
    int hwl = tid & 63, cb = tid >> 6;
    const float* s = src + (size_t)(c0 + cb) * 65536 + hwb + hwl;
#pragma unroll
    for (int i = 0; i < 16; ++i)
      T[cb + i * 4][hwl] = __float2bfloat16(s[(size_t)i * 4 * 65536]);
  }
  __syncthreads();
  {
    int cl = tid & 63, hb = tid >> 6;
#pragma unroll
    for (int j = 0; j < 16; ++j) {
      int hwl = hb + j * 4;
      int hw = hwb + hwl;
      int h = hw >> 8, w = hw & 255;
      int sw = swoff + ((h >> 3) << 5) + (w >> 3);
      int tt = ((h & 7) << 3) + (w & 7);
      qwM[((size_t)(sw * 64 + tt) << 8) + c0 + cl] = T[cl][hwl];
    }
  }
}

__device__ __forceinline__ void d_stagekv(int tile, int tid, const float* src,
                                          bf16* dst, char* SMEM) {
  bf16(*T)[66] = (bf16(*)[66])SMEM;
  int c0 = (tile & 3) << 6;
  int hwoff = (tile >> 2) << 6;
  {
    int hwl = tid & 63, cb = tid >> 6;
    const float* s = src + (size_t)(c0 + cb) * 65536 + hwoff + hwl;
#pragma unroll
    for (int i = 0; i < 16; ++i)
      T[cb + i * 4][hwl] = __float2bfloat16(s[(size_t)i * 4 * 65536]);
  }
  __syncthreads();
  {
    int cl = tid & 63, hb = tid >> 6;
#pragma unroll
    for (int j = 0; j < 16; ++j) {
      int hwl = hb + j * 4;
      dst[((size_t)(hwoff + hwl) << 8) + c0 + cl] = T[cl][hwl];
    }
  }
}

__device__ __forceinline__ void d_convkv(int ib, int cnt, int wid_base,
                                         int bufoff, int skmask, int tid,
                                         const bf16* SK, const float* wdw,
                                         const bf16* wkvT, const float* bkv,
                                         bf16* k_s, bf16* vT_s, char* SMEM) {
  bf16* X = (bf16*)SMEM;
  auto xp = [&](int row, int col) -> bf16* {
    int by = (row << 9) + (col << 1);
    by ^= (row & 7) << 4;
    return (bf16*)((char*)X + by);
  };
  int swc = (ib & 7) * (cnt >> 3) + (ib >> 3);
  int wid = wid_base + swc;
  int gw = wid - bufoff;
  int b = wid >> 10;
  int rem = wid & 1023, wh = rem >> 5, ww = rem & 31;
  int h0 = wh * 8, w0 = ww * 8;
  const bf16* SKb = SK + (size_t)(b & skmask) * 16777216;
  {  // phase A: depthwise conv, thread = channel (coalesced NHWC reads)
    int c = tid;
    float wr[9];
#pragma unroll
    for (int q = 0; q < 9; ++q) wr[q] = wdw[c * 9 + q];
    const bool wlo = (w0 > 0), whi = (w0 < 248);
    float rows[3][10];
    auto load_row = [&](int gh, float* r) {
      if (gh >= 0 && gh < 256) {
        const bf16* rp = SKb + ((size_t)(gh * 256 + w0) << 8) + c;
        r[0] = wlo ? __bfloat162float(rp[-256]) : 0.f;
#pragma unroll
        for (int s = 1; s <= 8; ++s) r[s] = __bfloat162float(rp[(s - 1) * 256]);
        r[9] = whi ? __bfloat162float(rp[8 * 256]) : 0.f;
      } else {
#pragma unroll
        for (int e = 0; e < 10; ++e) r[e] = 0.f;
      }
    };
    load_row(h0 - 1, rows[0]);
    load_row(h0, rows[1]);
#pragma unroll
    for (int i = 0; i < 8; ++i) {
      load_row(h0 + i + 1, rows[(i + 2) % 3]);
#pragma unroll
      for (int j = 0; j < 8; ++j) {
        float acc = 0.f;
#pragma unroll
        for (int di = 0; di < 3; ++di) {
          const float* rp = rows[(i + di) % 3];
          acc = __builtin_fmaf(wr[di * 3 + 0], rp[j], acc);
          acc = __builtin_fmaf(wr[di * 3 + 1], rp[j + 1], acc);
          acc = __builtin_fmaf(wr[di * 3 + 2], rp[j + 2], acc);
        }
        *xp(i * 8 + j, c) = __float2bfloat16(acc);
      }
    }
  }
  __syncthreads();
  int wave = tid >> 6, lane = tid & 63, quad = lane >> 4, l16 = lane & 15;
  int n0 = wave * 64;
  f32x4 zero4 = {0.f, 0.f, 0.f, 0.f};
  f32x4 acc[4][4];
  // ---- k pass (normal MFMA, D[token][c]) ----
  for (int mt = 0; mt < 4; ++mt)
    for (int nt = 0; nt < 4; ++nt) acc[mt][nt] = zero4;
  for (int k0 = 0; k0 < 256; k0 += 32) {
    bf16x8 a[4], bb[4];
    for (int mt = 0; mt < 4; ++mt)
      a[mt] = *(const bf16x8*)xp(mt * 16 + l16, k0 + quad * 8);
    for (int nt = 0; nt < 4; ++nt)
      bb[nt] = *(const bf16x8*)&wkvT[(size_t)(n0 + nt * 16 + l16) * 256 + k0 + quad * 8];
    for (int mt = 0; mt < 4; ++mt)
      for (int nt = 0; nt < 4; ++nt) acc[mt][nt] = MFMA(a[mt], bb[nt], acc[mt][nt]);
  }
  for (int nt = 0; nt < 4; ++nt) {
    int n = n0 + nt * 16 + l16;
    float bias = bkv[n];
    for (int mt = 0; mt < 4; ++mt) {
      int mb = mt * 16 + quad * 4;
      for (int r = 0; r < 4; ++r)
        k_s[((size_t)(gw * 64 + mb + r) << 8) + n] =
            __float2bfloat16(acc[mt][nt][r] + bias);
    }
  }
  // ---- v pass (swapped MFMA -> D[vdim][token], coalesced vT write) ----
  for (int mt = 0; mt < 4; ++mt)
    for (int nt = 0; nt < 4; ++nt) acc[mt][nt] = zero4;
  for (int k0 = 0; k0 < 256; k0 += 32) {
    bf16x8 a[4], bb[4];
    for (int mt = 0; mt < 4; ++mt)
      a[mt] = *(const bf16x8*)xp(mt * 16 + l16, k0 + quad * 8);
    for (int nt = 0; nt < 4; ++nt)
      bb[nt] = *(const bf16x8*)&wkvT[(size_t)(256 + n0 + nt * 16 + l16) * 256 + k0 + quad * 8];
    for (int mt = 0; mt < 4; ++mt)
      for (int nt = 0; nt < 4; ++nt) acc[mt][nt] = MFMA(bb[nt], a[mt], acc[mt][nt]);
  }
  for (int nt = 0; nt < 4; ++nt) {
    for (int r = 0; r < 4; ++r) {
      int vd = n0 + nt * 16 + quad * 4 + r;
      float bias = bkv[256 + vd];
      for (int mt = 0; mt < 4; ++mt)
        vT_s[((size_t)(gw * 256 + vd) << 6) + mt * 16 + l16] =
            __float2bfloat16(acc[mt][nt][r] + bias);
    }
  }
}

__device__ __forceinline__ void d_fused(int ib, int nw, int wid_base,
                                        int bufoff, int tid,
                                        const bf16* qwM, const bf16* wqT,
                                        const float* bq, const bf16* k_s,
                                        const bf16* vT_s, const bf16* wpT,
                                        const float* bp, float* out,
                                        char* SMEM) {
  bf16* XQ = (bf16*)SMEM;  // staged q, then per-wave q/P/O regions (overlay)
  int sw = (ib & 7) * (nw >> 3) + (ib >> 3);
  int wid = wid_base + sw;
  int gw = wid - bufoff;
  int b = wid >> 10, rem = wid & 1023, wh = rem >> 5, ww = rem & 31;
  int h0 = wh * 8, w0 = ww * 8;
  int wave = tid >> 6, lane = tid & 63, quad = lane >> 4, l16 = lane & 15;
  const bf16* kw = k_s + ((size_t)gw << 14);
  const bf16* vw = vT_s + ((size_t)gw << 14);

  // ---- issue XQ staging via global_load_lds (pre-swizzled source) ----
  {
    const char* Aq = (const char*)(qwM + ((size_t)gw << 14));
#pragma unroll
    for (int rr = 0; rr < 8; ++rr) {
      int L = rr * 4096 + wave * 1024 + lane * 16;
      int gl = L ^ (((L >> 9) & 7) << 4);
      __builtin_amdgcn_global_load_lds(
          (const __attribute__((address_space(1))) void*)(Aq + gl),
          (__attribute__((address_space(3))) void*)(SMEM + rr * 4096 + wave * 1024),
          16, 0, 0);
    }
  }
  // ---- prefetch k/v fragments into registers ----
  bf16x8 kfr[2][4], vfr[2][2][2];
#pragma unroll
  for (int hi = 0; hi < 2; ++hi) {
    int co = (wave + hi * 4) * 32;
#pragma unroll
    for (int nt = 0; nt < 4; ++nt)
      kfr[hi][nt] = *(const bf16x8*)&kw[(size_t)(nt * 16 + l16) * 256 + co + quad * 8];
#pragma unroll
    for (int half = 0; half < 2; ++half)
#pragma unroll
      for (int nt = 0; nt < 2; ++nt)
        vfr[hi][half][nt] =
            *(const bf16x8*)&vw[(size_t)(co + nt * 16 + l16) * 64 + half * 32 + quad * 8];
  }
  __syncthreads();  // B1: XQ staged (vmcnt drained), k/v frags in regs

  auto xq = [&](int row, int col) -> const bf16* {
    int by = (row << 9) + (col << 1);
    by ^= (row & 7) << 4;
    return (const bf16*)((const char*)XQ + by);
  };
  char* Abase = (char*)XQ + wave * 8192;
  auto ap = [&](int row, int col) -> bf16* {
    int by = (row << 7) + (col << 1);
    by ^= (row & 7) << 4;
    return (bf16*)(Abase + by);
  };
  auto apR = [&](int w, int row, int col) -> bf16* {
    int by = (row << 7) + (col << 1);
    by ^= (row & 7) << 4;
    return (bf16*)((char*)XQ + w * 8192 + by);
  };
  f32x4 zero4 = {0.f, 0.f, 0.f, 0.f};

  // ---- phase 1: q-proj K-loop (reads XQ; acc in registers) ----
  f32x4 qacc[4][4];
  for (int mt = 0; mt < 4; ++mt)
    for (int nt = 0; nt < 4; ++nt) qacc[mt][nt] = zero4;
  for (int k0 = 0; k0 < 256; k0 += 32) {
    bf16x8 a[4], bb[4];
    for (int mt = 0; mt < 4; ++mt)
      a[mt] = *(const bf16x8*)xq(mt * 16 + l16, k0 + quad * 8);
    for (int nt = 0; nt < 4; ++nt) {
      int n = (wave + ((nt >> 1) << 2)) * 32 + (nt & 1) * 16 + l16;
      bb[nt] = *(const bf16x8*)&wqT[(size_t)n * 256 + k0 + quad * 8];
    }
    for (int mt = 0; mt < 4; ++mt)
      for (int nt = 0; nt < 4; ++nt) qacc[mt][nt] = MFMA(a[mt], bb[nt], qacc[mt][nt]);
  }
  __syncthreads();  // B2: all waves done reading XQ -> overlay safe
  {
    const float scale = 0.1767766952966369f;  // 32^-0.5
    for (int nt = 0; nt < 4; ++nt) {
      int n = (wave + ((nt >> 1) << 2)) * 32 + (nt & 1) * 16 + l16;
      float bias = bq[n];
      for (int mt = 0; mt < 4; ++mt) {
        int mb = mt * 16 + quad * 4;
        for (int r = 0; r < 4; ++r)
          *ap(mb + r, nt * 16 + l16) =
              __float2bfloat16((qacc[mt][nt][r] + bias) * scale);
      }
    }
  }
  // ---- phase 2: attention, wave-private ----
#pragma unroll
  for (int hi = 0; hi < 2; ++hi) {
    int lc = hi * 32;
    f32x4 s[4][4];
    for (int mt = 0; mt < 4; ++mt)
      for (int nt = 0; nt < 4; ++nt) s[mt][nt] = zero4;
    {
      bf16x8 a[4];
      for (int mt = 0; mt < 4; ++mt)
        a[mt] = *(const bf16x8*)ap(mt * 16 + l16, lc + quad * 8);
      __builtin_amdgcn_s_setprio(1);
      for (int mt = 0; mt < 4; ++mt)
#pragma unroll
        for (int nt = 0; nt < 4; ++nt) s[mt][nt] = MFMA(a[mt], kfr[hi][nt], s[mt][nt]);
      __builtin_amdgcn_s_setprio(0);
    }
    float rsum[4][4];
    for (int mt = 0; mt < 4; ++mt) {
      for (int r = 0; r < 4; ++r) {
        float m = s[mt][0][r];
        for (int nt = 1; nt < 4; ++nt) m = fmaxf(m, s[mt][nt][r]);
        m = fmaxf(m, __shfl_xor(m, 1, 64));
        m = fmaxf(m, __shfl_xor(m, 2, 64));
        m = fmaxf(m, __shfl_xor(m, 4, 64));
        m = fmaxf(m, __shfl_xor(m, 8, 64));
        float sum = 0.f;
        for (int nt = 0; nt < 4; ++nt) {
          float e = __expf(s[mt][nt][r] - m);
          s[mt][nt][r] = e;
          sum += e;
        }
        sum += __shfl_xor(sum, 1, 64);
        sum += __shfl_xor(sum, 2, 64);
        sum += __shfl_xor(sum, 4, 64);
        sum += __shfl_xor(sum, 8, 64);
        rsum[mt][r] = sum;
      }
    }
    // PV through the just-dead q columns [lc, lc+32), two k-halves
    f32x4 o[4][2];
    for (int mt = 0; mt < 4; ++mt)
      for (int nt = 0; nt < 2; ++nt) o[mt][nt] = zero4;
#pragma unroll
    for (int half = 0; half < 2; ++half) {
      for (int mt = 0; mt < 4; ++mt)
#pragma unroll
        for (int nt2 = 0; nt2 < 2; ++nt2)
          for (int r = 0; r < 4; ++r)
            *ap(mt * 16 + quad * 4 + r, lc + nt2 * 16 + l16) =
                __float2bfloat16(s[mt][half * 2 + nt2][r]);
      bf16x8 pa[4];
      for (int mt = 0; mt < 4; ++mt)
        pa[mt] = *(const bf16x8*)ap(mt * 16 + l16, lc + quad * 8);
      __builtin_amdgcn_s_setprio(1);
      for (int mt = 0; mt < 4; ++mt)
#pragma unroll
        for (int nt = 0; nt < 2; ++nt)
          o[mt][nt] = MFMA(pa[mt], vfr[hi][half][nt], o[mt][nt]);
      __builtin_amdgcn_s_setprio(0);
    }
    for (int mt = 0; mt < 4; ++mt) {
      int mb = mt * 16 + quad * 4;
      for (int nt = 0; nt < 2; ++nt)
        for (int r = 0; r < 4; ++r)
          *ap(mb + r, lc + nt * 16 + l16) =
              __float2bfloat16(o[mt][nt][r] / rsum[mt][r]);
    }
  }
  __syncthreads();  // B3: O gathered cross-wave below
  // ---- phase 3: out-projection -> NCHW f32 ----
  {
    int n0 = wave * 64;
    f32x4 acc[4][4];
    for (int mt = 0; mt < 4; ++mt)
      for (int nt = 0; nt < 4; ++nt) acc[mt][nt] = zero4;
    for (int k0 = 0; k0 < 256; k0 += 32) {
      int head = k0 >> 5;
      int rw = head & 3;
      int lc = (head >> 2) * 32;
      bf16x8 a[4], bb[4];
      for (int mt = 0; mt < 4; ++mt)
        a[mt] = *(const bf16x8*)apR(rw, mt * 16 + l16, lc + quad * 8);
      for (int nt = 0; nt < 4; ++nt)
        bb[nt] = *(const bf16x8*)&wpT[(size_t)(n0 + nt * 16 + l16) * 256 + k0 + quad * 8];
      for (int mt = 0; mt < 4; ++mt)
        for (int nt = 0; nt < 4; ++nt) acc[mt][nt] = MFMA(a[mt], bb[nt], acc[mt][nt]);
    }
    for (int nt = 0; nt < 4; ++nt) {
      int n = n0 + nt * 16 + l16;
      float bias = bp[n];
      float* chan = out + ((size_t)(b * 256 + n) << 16);
      for (int mt = 0; mt < 4; ++mt) {
        int row_i = mt * 2 + (quad >> 1);
        int j0 = (quad & 1) * 4;
        f32x4 v4;
        for (int r = 0; r < 4; ++r) v4[r] = acc[mt][nt][r] + bias;
        *(f32x4*)&chan[(size_t)(h0 + row_i) * 256 + w0 + j0] = v4;
      }
    }
  }
}

// ===========================================================================
// pipe_k: block-range dispatch. Ranges in bid order:
//   [wtrans (1024 if do_w)] [conv nconv] [fused nfused] [stage_q nsq] [stage_kv nskv]
// grid must equal the sum. Co-schedules independent pipeline stages.
// ===========================================================================
__global__ __launch_bounds__(256) void pipe_k(
    int do_w, int nconv, int conv_wb, int nfused, int fused_wb,
    int nsq, const float* sqsrc, int sq_swoff,
    int nskv, const float* skvsrc, bf16* skvdst,
    int bufoff, int skmask,
    const float* wq, const float* wkv, const float* wp,
    bf16* wqT, bf16* wkvT, bf16* wpT,
    const bf16* SK, const float* wdw, const float* bkv,
    bf16* qwM, const float* bq,
    bf16* KS, bf16* VT, const float* bp, float* out) {
  __shared__ __align__(16) char SMEM[32768];
  int bid = blockIdx.x, tid = threadIdx.x;
  int wb = do_w ? 1024 : 0;
  if (bid < wb) {
    d_wtrans(bid * 256 + tid, wq, wkv, wp, wqT, wkvT, wpT);
    return;
  }
  bid -= wb;
  if (bid < nconv) {
    d_convkv(bid, nconv, conv_wb, bufoff, skmask, tid, SK, wdw, wkvT, bkv, KS,
             VT, SMEM);
    return;
  }
  bid -= nconv;
  if (bid < nfused) {
    d_fused(bid, nfused, fused_wb, bufoff, tid, qwM, wqT, bq, KS, VT, wpT, bp,
            out, SMEM);
    return;
  }
  bid -= nfused;
  if (bid < nsq) {
    d_stageq(bid, tid, sqsrc, qwM, sq_swoff, SMEM);
    return;
  }
  bid -= nsq;
  if (bid < nskv) {
    d_stagekv(bid, tid, skvsrc, skvdst, SMEM);
  }
}

// ===========================================================================
extern "C" void kernel_launch(void* const* d_in, const int* in_sizes, int n_in,
                              void* d_out, int out_size, void* d_ws, size_t ws_size,
                              hipStream_t stream) {
  const float* qf  = (const float*)d_in[0];
  const float* kvf = (const float*)d_in[1];
  const float* wdw = (const float*)d_in[2];
  const float* wq  = (const float*)d_in[3];
  const float* bq  = (const float*)d_in[4];
  const float* wkv = (const float*)d_in[5];
  const float* bkv = (const float*)d_in[6];
  const float* wp  = (const float*)d_in[7];
  const float* bp  = (const float*)d_in[8];
  float* out = (float*)d_out;

  bf16* wqT  = (bf16*)d_ws;
  bf16* wkvT = wqT + 65536;
  bf16* wpT  = wkvT + 131072;
  bf16* bufs = wpT + 65536;
  const size_t welems = 65536 + 131072 + 65536;
  const size_t skel = (size_t)256 * 256 * 256;  // one NHWC batch image

  const float* q0 = qf;
  const float* q1 = qf + ((size_t)1 << 24);
  const float* k0 = kvf;
  const float* k1 = kvf + ((size_t)1 << 24);

  // ---- fits-path: 4-dispatch batch-pipelined schedule ----
  size_t fitelems = welems + 2 * skel + (size_t)3 * 2048 * 16384;
  if (fitelems * 2 <= ws_size) {
    bf16* SK  = bufs;
    bf16* qwM = SK + 2 * skel;
    bf16* KS  = qwM + (size_t)2048 * 16384;
    bf16* VT  = KS + (size_t)2048 * 16384;
    // D1: wtrans | stage_q(b0) | stage_kv(b0)
    pipe_k<<<1024 + 4096 + 4096, 256, 0, stream>>>(
        1, 0, 0, 0, 0, 4096, q0, 0, 4096, k0, SK, 0, 1,
        wq, wkv, wp, wqT, wkvT, wpT, SK, wdw, bkv, qwM, bq, KS, VT, bp, out);
    // D2: convkv(b0) | stage_q(b1) | stage_kv(b1)
    pipe_k<<<1024 + 4096 + 4096, 256, 0, stream>>>(
        0, 1024, 0, 0, 0, 4096, q1, 1024, 4096, k1, SK + skel, 0, 1,
        wq, wkv, wp, wqT, wkvT, wpT, SK, wdw, bkv, qwM, bq, KS, VT, bp, out);
    // D3: convkv(b1) | fused(b0)
    pipe_k<<<2048, 256, 0, stream>>>(
        0, 1024, 1024, 1024, 0, 0, q0, 0, 0, k0, SK, 0, 1,
        wq, wkv, wp, wqT, wkvT, wpT, SK, wdw, bkv, qwM, bq, KS, VT, bp, out);
    // D4: fused(b1)
    pipe_k<<<1024, 256, 0, stream>>>(
        0, 0, 0, 1024, 1024, 0, q0, 0, 0, k0, SK, 0, 1,
        wq, wkv, wp, wqT, wkvT, wpT, SK, wdw, bkv, qwM, bq, KS, VT, bp, out);
    return;
  }

  // ---- fallback: per-batch serial (1 SK slot, 1024-window buffers) ----
  {
    bf16* SK  = bufs;
    bf16* qwM = SK + skel;
    bf16* KS  = qwM + (size_t)1024 * 16384;
    bf16* VT  = KS + (size_t)1024 * 16384;
    for (int b = 0; b < 2; ++b) {
      const float* qb = b ? q1 : q0;
      const float* kb = b ? k1 : k0;
      int bo = b * 1024;
      // stage (wtrans only on first pass)
      pipe_k<<<(b == 0 ? 1024 : 0) + 4096 + 4096, 256, 0, stream>>>(
          b == 0 ? 1 : 0, 0, 0, 0, 0, 4096, qb, 0, 4096, kb, SK, bo, 0,
          wq, wkv, wp, wqT, wkvT, wpT, SK, wdw, bkv, qwM, bq, KS, VT, bp, out);
      // convkv
      pipe_k<<<1024, 256, 0, stream>>>(
          0, 1024, bo, 0, 0, 0, qb, 0, 0, kb, SK, bo, 0,
          wq, wkv, wp, wqT, wkvT, wpT, SK, wdw, bkv, qwM, bq, KS, VT, bp, out);
      // fused
      pipe_k<<<1024, 256, 0, stream>>>(
          0, 0, 0, 1024, bo, 0, qb, 0, 0, kb, SK, bo, 0,
          wq, wkv, wp, wqT, wkvT, wpT, SK, wdw, bkv, qwM, bq, KS, VT, bp, out);
    }
  }
}

// Round 14
// 567.671 us; speedup vs baseline: 1.2457x; 1.2457x over previous
//
#include <hip/hip_runtime.h>
#include <hip/hip_bf16.h>
#include <cstdint>
#include <cstddef>

typedef __hip_bfloat16 bf16;
typedef short bf16x8 __attribute__((ext_vector_type(8)));
typedef float f32x4 __attribute__((ext_vector_type(4)));

#define MFMA(a, b, c) __builtin_amdgcn_mfma_f32_16x16x32_bf16((a), (b), (c), 0, 0, 0)

// ---------------------------------------------------------------------------
// MERGED stage kernel (fits-path): block-range dispatch.
//   blocks [0, 1024):            weight transposes
//   blocks [1024, 1024+nb*4096): q gather-transpose -> window-major qwM
//   blocks [.., +nb*4096):       kv NCHW -> NHWC (SK slot = batch & skmask)
// ---------------------------------------------------------------------------
__global__ __launch_bounds__(256) void stage_k(
    const float* __restrict__ wq, const float* __restrict__ wkv,
    const float* __restrict__ wp, bf16* __restrict__ wqT,
    bf16* __restrict__ wkvT, bf16* __restrict__ wpT,
    const float* __restrict__ qf, bf16* __restrict__ qwM,
    const float* __restrict__ kvf, bf16* __restrict__ SK,
    int b0, int nb, int skmask, int wbP, int do_w) {
  __shared__ bf16 T[64][66];
  int bid = blockIdx.x;
  int tid = threadIdx.x;
  int wb = do_w ? 1024 : 0;
  if (bid < wb) {
    int idx = bid * 256 + tid;
    if (idx < 65536) {
      int n = idx >> 8, k = idx & 255;
      wqT[idx] = __float2bfloat16(wq[k * 256 + n]);
    } else if (idx < 196608) {
      int i = idx - 65536;
      int n = i >> 8, k = i & 255;
      wkvT[i] = __float2bfloat16(wkv[k * 512 + n]);
    } else {
      int i = idx - 196608;
      int n = i >> 8, k = i & 255;
      wpT[i] = __float2bfloat16(wp[k * 256 + n]);
    }
    return;
  }
  int tile = bid - wb;
  int qtiles = nb * 4096;
  if (tile < qtiles) {  // ---- q gather-transpose ----
    int b = b0 + (tile >> 12);
    int t = tile & 4095;
    int c0 = (t & 3) << 6;
    int hwb = (t >> 2) << 6;
    const float* src = qf + ((size_t)b << 24);
    {
      int hwl = tid & 63, cb = tid >> 6;
      const float* s = src + (size_t)(c0 + cb) * 65536 + hwb + hwl;
#pragma unroll
      for (int i = 0; i < 16; ++i)
        T[cb + i * 4][hwl] = __float2bfloat16(s[(size_t)i * 4 * 65536]);
    }
    __syncthreads();
    {
      int cl = tid & 63, hb = tid >> 6;
      int swoff = b * 1024 - wbP;
#pragma unroll
      for (int j = 0; j < 16; ++j) {
        int hwl = hb + j * 4;
        int hw = hwb + hwl;
        int h = hw >> 8, w = hw & 255;
        int sw = swoff + ((h >> 3) << 5) + (w >> 3);
        int tt = ((h & 7) << 3) + (w & 7);
        qwM[((size_t)(sw * 64 + tt) << 8) + c0 + cl] = T[cl][hwl];
      }
    }
  } else {  // ---- kv NCHW -> NHWC ----
    tile -= qtiles;
    int b = b0 + (tile >> 12);
    int t = tile & 4095;
    int c0 = (t & 3) << 6;
    int hwoff = (t >> 2) << 6;
    const float* src = kvf + ((size_t)b << 24);
    bf16* dst = SK + (size_t)(b & skmask) * 16777216;
    {
      int hwl = tid & 63, cb = tid >> 6;
      const float* s = src + (size_t)(c0 + cb) * 65536 + hwoff + hwl;
#pragma unroll
      for (int i = 0; i < 16; ++i)
        T[cb + i * 4][hwl] = __float2bfloat16(s[(size_t)i * 4 * 65536]);
    }
    __syncthreads();
    {
      int cl = tid & 63, hb = tid >> 6;
#pragma unroll
      for (int j = 0; j < 16; ++j) {
        int hwl = hb + j * 4;
        dst[((size_t)(hwoff + hwl) << 8) + c0 + cl] = T[cl][hwl];
      }
    }
  }
}

// ---------------------------------------------------------------------------
// Fallback-path kernels: wtrans_k, t_winq_k, t_nhwc_k.
// ---------------------------------------------------------------------------
__global__ __launch_bounds__(256) void wtrans_k(const float* __restrict__ wq,
                                                const float* __restrict__ wkv,
                                                const float* __restrict__ wp,
                                                bf16* __restrict__ wqT,
                                                bf16* __restrict__ wkvT,
                                                bf16* __restrict__ wpT) {
  int idx = blockIdx.x * 256 + threadIdx.x;
  if (idx < 65536) {
    int n = idx >> 8, k = idx & 255;
    wqT[idx] = __float2bfloat16(wq[k * 256 + n]);
  } else if (idx < 196608) {
    int i = idx - 65536;
    int n = i >> 8, k = i & 255;
    wkvT[i] = __float2bfloat16(wkv[k * 512 + n]);
  } else {
    int i = idx - 196608;
    int n = i >> 8, k = i & 255;
    wpT[i] = __float2bfloat16(wp[k * 256 + n]);
  }
}

__global__ __launch_bounds__(256) void t_winq_k(const float* __restrict__ src,
                                                bf16* __restrict__ dst,
                                                int hw0, int swoff) {
  __shared__ bf16 T[64][66];
  int tile = blockIdx.x;
  int c0 = (tile & 3) << 6;
  int hwb = hw0 + ((tile >> 2) << 6);
  int tid = threadIdx.x;
  {
    int hwl = tid & 63, cb = tid >> 6;
    const float* s = src + (size_t)(c0 + cb) * 65536 + hwb + hwl;
#pragma unroll
    for (int i = 0; i < 16; ++i)
      T[cb + i * 4][hwl] = __float2bfloat16(s[(size_t)i * 4 * 65536]);
  }
  __syncthreads();
  {
    int cl = tid & 63, hb = tid >> 6;
#pragma unroll
    for (int j = 0; j < 16; ++j) {
      int hwl = hb + j * 4;
      int hw = hwb + hwl;
      int h = hw >> 8, w = hw & 255;
      int sw = swoff + ((h >> 3) << 5) + (w >> 3);
      int t = ((h & 7) << 3) + (w & 7);
      dst[((size_t)(sw * 64 + t) << 8) + c0 + cl] = T[cl][hwl];
    }
  }
}

__global__ __launch_bounds__(256) void t_nhwc_k(const float* __restrict__ src,
                                                bf16* __restrict__ dst) {
  __shared__ bf16 T[64][66];
  int tile = blockIdx.x;
  int c0 = (tile & 3) << 6;
  int hwoff = (tile >> 2) << 6;
  int tid = threadIdx.x;
  {
    int hwl = tid & 63, cb = tid >> 6;
    const float* s = src + (size_t)(c0 + cb) * 65536 + hwoff + hwl;
#pragma unroll
    for (int i = 0; i < 16; ++i)
      T[cb + i * 4][hwl] = __float2bfloat16(s[(size_t)i * 4 * 65536]);
  }
  __syncthreads();
  {
    int cl = tid & 63, hb = tid >> 6;
#pragma unroll
    for (int j = 0; j < 16; ++j) {
      int hwl = hb + j * 4;
      dst[((size_t)(hwoff + hwl) << 8) + c0 + cl] = T[cl][hwl];
    }
  }
}

// ---------------------------------------------------------------------------
// K1: FUSED conv + kv projection. Conv phase VECTORIZED: 2 channels/thread,
// bf16x2 (uint32) loads -> 256B/wave coalesced, 60 loads/thread (was 100
// scalar 2B). FMA tap order preserved (bit-identical results).
// X tile [64][256] bf16, XOR-swizzled (byte ^= (row&7)<<4).
// ---------------------------------------------------------------------------
__global__ __launch_bounds__(256) void convkv_k(const bf16* __restrict__ SK,
                                                const float* __restrict__ wdw,
                                                const bf16* __restrict__ wkvT,
                                                const float* __restrict__ bkv,
                                                bf16* __restrict__ k_s,
                                                bf16* __restrict__ vT_s,
                                                int wid_base, int cnt, int psw0,
                                                int skmask) {
  __shared__ __align__(16) bf16 X[64 * 256];
  auto xp = [&](int row, int col) -> bf16* {
    int by = (row << 9) + (col << 1);
    by ^= (row & 7) << 4;
    return (bf16*)((char*)X + by);
  };
  int bid = blockIdx.x;
  int swc = (bid & 7) * (cnt >> 3) + (bid >> 3);
  int sw = psw0 + swc;
  int wid = wid_base + swc;
  int b = wid >> 10;
  int rem = wid & 1023, wh = rem >> 5, ww = rem & 31;
  int h0 = wh * 8, w0 = ww * 8;
  const bf16* SKb = SK + (size_t)(b & skmask) * 16777216;
  int tid = threadIdx.x;
  {  // phase A: conv, 2 channels/thread, bf16x2 vector loads
    int tg = tid >> 7;   // token-row group: i = tg*4 + ir
    int cg = tid & 127;  // channel pair: c = {cg*2, cg*2+1}
    float wr0[9], wr1[9];
#pragma unroll
    for (int q = 0; q < 9; ++q) {
      wr0[q] = wdw[(cg * 2) * 9 + q];
      wr1[q] = wdw[(cg * 2 + 1) * 9 + q];
    }
    const bool wlo = (w0 > 0), whi = (w0 < 248);  // wave-uniform
    float rows[3][10][2];
    auto load_row = [&](int gh, float (*r)[2]) {
      if (gh >= 0 && gh < 256) {  // wave-uniform (tg uniform per wave)
        const bf16* rp = SKb + ((size_t)(gh * 256 + w0) << 8) + cg * 2;
        auto up = [&](int off, float* d) {
          uint32_t v = *(const uint32_t*)&rp[off];
          d[0] = __uint_as_float(v << 16);
          d[1] = __uint_as_float(v & 0xffff0000u);
        };
        if (wlo) up(-256, r[0]); else { r[0][0] = 0.f; r[0][1] = 0.f; }
#pragma unroll
        for (int s = 1; s <= 8; ++s) up((s - 1) * 256, r[s]);
        if (whi) up(8 * 256, r[9]); else { r[9][0] = 0.f; r[9][1] = 0.f; }
      } else {
#pragma unroll
        for (int e = 0; e < 10; ++e) { r[e][0] = 0.f; r[e][1] = 0.f; }
      }
    };
    int hb = h0 + tg * 4;
    load_row(hb - 1, rows[0]);
    load_row(hb, rows[1]);
#pragma unroll
    for (int ir = 0; ir < 4; ++ir) {
      load_row(hb + ir + 1, rows[(ir + 2) % 3]);
#pragma unroll
      for (int j = 0; j < 8; ++j) {
        float a0 = 0.f, a1 = 0.f;
#pragma unroll
        for (int di = 0; di < 3; ++di) {
          const float(*rp)[2] = rows[(ir + di) % 3];
#pragma unroll
          for (int dj = 0; dj < 3; ++dj) {
            a0 = __builtin_fmaf(wr0[di * 3 + dj], rp[j + dj][0], a0);
            a1 = __builtin_fmaf(wr1[di * 3 + dj], rp[j + dj][1], a1);
          }
        }
        bf16* p = xp((tg * 4 + ir) * 8 + j, cg * 2);
        p[0] = __float2bfloat16(a0);
        p[1] = __float2bfloat16(a1);
      }
    }
  }
  __syncthreads();
  int wave = tid >> 6, lane = tid & 63, quad = lane >> 4, l16 = lane & 15;
  int n0 = wave * 64;
  f32x4 zero4 = {0.f, 0.f, 0.f, 0.f};
  f32x4 acc[4][4];
  // ---- k pass (normal MFMA, D[token][c]) ----
  for (int mt = 0; mt < 4; ++mt)
    for (int nt = 0; nt < 4; ++nt) acc[mt][nt] = zero4;
  for (int k0 = 0; k0 < 256; k0 += 32) {
    bf16x8 a[4], bb[4];
    for (int mt = 0; mt < 4; ++mt)
      a[mt] = *(const bf16x8*)xp(mt * 16 + l16, k0 + quad * 8);
    for (int nt = 0; nt < 4; ++nt)
      bb[nt] = *(const bf16x8*)&wkvT[(size_t)(n0 + nt * 16 + l16) * 256 + k0 + quad * 8];
    for (int mt = 0; mt < 4; ++mt)
      for (int nt = 0; nt < 4; ++nt) acc[mt][nt] = MFMA(a[mt], bb[nt], acc[mt][nt]);
  }
  for (int nt = 0; nt < 4; ++nt) {
    int n = n0 + nt * 16 + l16;
    float bias = bkv[n];
    for (int mt = 0; mt < 4; ++mt) {
      int mb = mt * 16 + quad * 4;
      for (int r = 0; r < 4; ++r)
        k_s[((size_t)(sw * 64 + mb + r) << 8) + n] =
            __float2bfloat16(acc[mt][nt][r] + bias);
    }
  }
  // ---- v pass (swapped MFMA -> D[vdim][token], coalesced vT write) ----
  for (int mt = 0; mt < 4; ++mt)
    for (int nt = 0; nt < 4; ++nt) acc[mt][nt] = zero4;
  for (int k0 = 0; k0 < 256; k0 += 32) {
    bf16x8 a[4], bb[4];
    for (int mt = 0; mt < 4; ++mt)
      a[mt] = *(const bf16x8*)xp(mt * 16 + l16, k0 + quad * 8);
    for (int nt = 0; nt < 4; ++nt)
      bb[nt] = *(const bf16x8*)&wkvT[(size_t)(256 + n0 + nt * 16 + l16) * 256 + k0 + quad * 8];
    for (int mt = 0; mt < 4; ++mt)
      for (int nt = 0; nt < 4; ++nt) acc[mt][nt] = MFMA(bb[nt], a[mt], acc[mt][nt]);
  }
  for (int nt = 0; nt < 4; ++nt) {
    for (int r = 0; r < 4; ++r) {
      int vd = n0 + nt * 16 + quad * 4 + r;
      float bias = bkv[256 + vd];
      for (int mt = 0; mt < 4; ++mt)
        vT_s[((size_t)(sw * 256 + vd) << 6) + mt * 16 + l16] =
            __float2bfloat16(acc[mt][nt][r] + bias);
    }
  }
}

// ---------------------------------------------------------------------------
// K2: FUSED q-proj + attention + out-proj (R11 overlay structure + setprio).
// ---------------------------------------------------------------------------
__global__ __launch_bounds__(256, 2) void fused_k(const bf16* __restrict__ qwM,
                                                  const bf16* __restrict__ wqT,
                                                  const float* __restrict__ bq,
                                                  const bf16* __restrict__ k_s,
                                                  const bf16* __restrict__ vT_s,
                                                  const bf16* __restrict__ wpT,
                                                  const float* __restrict__ bp,
                                                  float* __restrict__ out,
                                                  int wid_base, int nw) {
  __shared__ __align__(16) bf16 XQ[64 * 256];  // staged q, then q/P/O regions
  int bid = blockIdx.x;
  int sw = (bid & 7) * (nw >> 3) + (bid >> 3);
  int wid = wid_base + sw;
  int b = wid >> 10, rem = wid & 1023, wh = rem >> 5, ww = rem & 31;
  int h0 = wh * 8, w0 = ww * 8;
  int tid = threadIdx.x, wave = tid >> 6, lane = tid & 63, quad = lane >> 4, l16 = lane & 15;
  const bf16* kw = k_s + ((size_t)sw << 14);
  const bf16* vw = vT_s + ((size_t)sw << 14);

  // ---- issue XQ staging: fire-and-forget global_load_lds ----
  {
    const char* Aq = (const char*)(qwM + ((size_t)sw << 14));
#pragma unroll
    for (int rr = 0; rr < 8; ++rr) {
      int L = rr * 4096 + wave * 1024 + lane * 16;
      int gl = L ^ (((L >> 9) & 7) << 4);  // pre-swizzled source
      __builtin_amdgcn_global_load_lds(
          (const __attribute__((address_space(1))) void*)(Aq + gl),
          (__attribute__((address_space(3))) void*)((char*)XQ + rr * 4096 + wave * 1024),
          16, 0, 0);
    }
  }
  // ---- prefetch all k/v fragments into registers ----
  bf16x8 kfr[2][4], vfr[2][2][2];
#pragma unroll
  for (int hi = 0; hi < 2; ++hi) {
    int co = (wave + hi * 4) * 32;
#pragma unroll
    for (int nt = 0; nt < 4; ++nt)
      kfr[hi][nt] = *(const bf16x8*)&kw[(size_t)(nt * 16 + l16) * 256 + co + quad * 8];
#pragma unroll
    for (int half = 0; half < 2; ++half)
#pragma unroll
      for (int nt = 0; nt < 2; ++nt)
        vfr[hi][half][nt] =
            *(const bf16x8*)&vw[(size_t)(co + nt * 16 + l16) * 64 + half * 32 + quad * 8];
  }
  __syncthreads();  // B1: XQ staged (vmcnt drained), k/v frags in regs

  auto xq = [&](int row, int col) -> const bf16* {
    int by = (row << 9) + (col << 1);
    by ^= (row & 7) << 4;
    return (const bf16*)((const char*)XQ + by);
  };
  char* Abase = (char*)XQ + wave * 8192;  // per-wave region overlays XQ
  auto ap = [&](int row, int col) -> bf16* {
    int by = (row << 7) + (col << 1);
    by ^= (row & 7) << 4;
    return (bf16*)(Abase + by);
  };
  auto apR = [&](int w, int row, int col) -> bf16* {
    int by = (row << 7) + (col << 1);
    by ^= (row & 7) << 4;
    return (bf16*)((char*)XQ + w * 8192 + by);
  };
  f32x4 zero4 = {0.f, 0.f, 0.f, 0.f};

  // ---- phase 1: q-proj K-loop (reads XQ; acc stays in registers) ----
  f32x4 qacc[4][4];
  for (int mt = 0; mt < 4; ++mt)
    for (int nt = 0; nt < 4; ++nt) qacc[mt][nt] = zero4;
  for (int k0 = 0; k0 < 256; k0 += 32) {
    bf16x8 a[4], bb[4];
    for (int mt = 0; mt < 4; ++mt)
      a[mt] = *(const bf16x8*)xq(mt * 16 + l16, k0 + quad * 8);
    for (int nt = 0; nt < 4; ++nt) {
      int n = (wave + ((nt >> 1) << 2)) * 32 + (nt & 1) * 16 + l16;
      bb[nt] = *(const bf16x8*)&wqT[(size_t)n * 256 + k0 + quad * 8];
    }
    for (int mt = 0; mt < 4; ++mt)
      for (int nt = 0; nt < 4; ++nt) qacc[mt][nt] = MFMA(a[mt], bb[nt], qacc[mt][nt]);
  }
  __syncthreads();  // B2: all waves done reading XQ -> overlay safe
  {
    const float scale = 0.1767766952966369f;  // 32^-0.5
    for (int nt = 0; nt < 4; ++nt) {
      int n = (wave + ((nt >> 1) << 2)) * 32 + (nt & 1) * 16 + l16;
      float bias = bq[n];
      for (int mt = 0; mt < 4; ++mt) {
        int mb = mt * 16 + quad * 4;
        for (int r = 0; r < 4; ++r)
          *ap(mb + r, nt * 16 + l16) =
              __float2bfloat16((qacc[mt][nt][r] + bias) * scale);
      }
    }
  }
  // ---- phase 2: attention, wave-private ----
#pragma unroll
  for (int hi = 0; hi < 2; ++hi) {
    int lc = hi * 32;
    f32x4 s[4][4];
    for (int mt = 0; mt < 4; ++mt)
      for (int nt = 0; nt < 4; ++nt) s[mt][nt] = zero4;
    {
      bf16x8 a[4];
      for (int mt = 0; mt < 4; ++mt)
        a[mt] = *(const bf16x8*)ap(mt * 16 + l16, lc + quad * 8);
      __builtin_amdgcn_s_setprio(1);
      for (int mt = 0; mt < 4; ++mt)
#pragma unroll
        for (int nt = 0; nt < 4; ++nt) s[mt][nt] = MFMA(a[mt], kfr[hi][nt], s[mt][nt]);
      __builtin_amdgcn_s_setprio(0);
    }
    float rsum[4][4];
    for (int mt = 0; mt < 4; ++mt) {
      for (int r = 0; r < 4; ++r) {
        float m = s[mt][0][r];
        for (int nt = 1; nt < 4; ++nt) m = fmaxf(m, s[mt][nt][r]);
        m = fmaxf(m, __shfl_xor(m, 1, 64));
        m = fmaxf(m, __shfl_xor(m, 2, 64));
        m = fmaxf(m, __shfl_xor(m, 4, 64));
        m = fmaxf(m, __shfl_xor(m, 8, 64));
        float sum = 0.f;
        for (int nt = 0; nt < 4; ++nt) {
          float e = __expf(s[mt][nt][r] - m);
          s[mt][nt][r] = e;
          sum += e;
        }
        sum += __shfl_xor(sum, 1, 64);
        sum += __shfl_xor(sum, 2, 64);
        sum += __shfl_xor(sum, 4, 64);
        sum += __shfl_xor(sum, 8, 64);
        rsum[mt][r] = sum;
      }
    }
    // PV through the just-dead q columns [lc, lc+32), two k-halves
    f32x4 o[4][2];
    for (int mt = 0; mt < 4; ++mt)
      for (int nt = 0; nt < 2; ++nt) o[mt][nt] = zero4;
#pragma unroll
    for (int half = 0; half < 2; ++half) {
      for (int mt = 0; mt < 4; ++mt)
#pragma unroll
        for (int nt2 = 0; nt2 < 2; ++nt2)
          for (int r = 0; r < 4; ++r)
            *ap(mt * 16 + quad * 4 + r, lc + nt2 * 16 + l16) =
                __float2bfloat16(s[mt][half * 2 + nt2][r]);
      bf16x8 pa[4];
      for (int mt = 0; mt < 4; ++mt)
        pa[mt] = *(const bf16x8*)ap(mt * 16 + l16, lc + quad * 8);
      __builtin_amdgcn_s_setprio(1);
      for (int mt = 0; mt < 4; ++mt)
#pragma unroll
        for (int nt = 0; nt < 2; ++nt)
          o[mt][nt] = MFMA(pa[mt], vfr[hi][half][nt], o[mt][nt]);
      __builtin_amdgcn_s_setprio(0);
    }
    for (int mt = 0; mt < 4; ++mt) {
      int mb = mt * 16 + quad * 4;
      for (int nt = 0; nt < 2; ++nt)
        for (int r = 0; r < 4; ++r)
          *ap(mb + r, lc + nt * 16 + l16) =
              __float2bfloat16(o[mt][nt][r] / rsum[mt][r]);
    }
  }
  __syncthreads();  // B3: O gathered cross-wave below
  // ---- phase 3: out-projection -> NCHW f32 ----
  {
    int n0 = wave * 64;
    f32x4 acc[4][4];
    for (int mt = 0; mt < 4; ++mt)
      for (int nt = 0; nt < 4; ++nt) acc[mt][nt] = zero4;
    for (int k0 = 0; k0 < 256; k0 += 32) {
      int head = k0 >> 5;
      int rw = head & 3;
      int lc = (head >> 2) * 32;
      bf16x8 a[4], bb[4];
      for (int mt = 0; mt < 4; ++mt)
        a[mt] = *(const bf16x8*)apR(rw, mt * 16 + l16, lc + quad * 8);
      for (int nt = 0; nt < 4; ++nt)
        bb[nt] = *(const bf16x8*)&wpT[(size_t)(n0 + nt * 16 + l16) * 256 + k0 + quad * 8];
      for (int mt = 0; mt < 4; ++mt)
        for (int nt = 0; nt < 4; ++nt) acc[mt][nt] = MFMA(a[mt], bb[nt], acc[mt][nt]);
    }
    for (int nt = 0; nt < 4; ++nt) {
      int n = n0 + nt * 16 + l16;
      float bias = bp[n];
      float* chan = out + ((size_t)(b * 256 + n) << 16);
      for (int mt = 0; mt < 4; ++mt) {
        int row_i = mt * 2 + (quad >> 1);
        int j0 = (quad & 1) * 4;
        f32x4 v4;
        for (int r = 0; r < 4; ++r) v4[r] = acc[mt][nt][r] + bias;
        *(f32x4*)&chan[(size_t)(h0 + row_i) * 256 + w0 + j0] = v4;
      }
    }
  }
}

// ---------------------------------------------------------------------------
extern "C" void kernel_launch(void* const* d_in, const int* in_sizes, int n_in,
                              void* d_out, int out_size, void* d_ws, size_t ws_size,
                              hipStream_t stream) {
  const float* qf  = (const float*)d_in[0];
  const float* kvf = (const float*)d_in[1];
  const float* wdw = (const float*)d_in[2];
  const float* wq  = (const float*)d_in[3];
  const float* bq  = (const float*)d_in[4];
  const float* wkv = (const float*)d_in[5];
  const float* bkv = (const float*)d_in[6];
  const float* wp  = (const float*)d_in[7];
  const float* bp  = (const float*)d_in[8];
  float* out = (float*)d_out;

  bf16* wqT  = (bf16*)d_ws;
  bf16* wkvT = wqT + 65536;
  bf16* wpT  = wkvT + 131072;
  bf16* bufs = wpT + 65536;
  const size_t welems = 65536 + 131072 + 65536;
  const size_t skel = (size_t)256 * 256 * 256;  // one NHWC batch image (elems)

  // ---- fits-path: 3 dispatches (stage -> convkv -> fused) ----
  size_t fitelems = welems + 2 * skel + (size_t)3 * 2048 * 16384;
  if (fitelems * 2 <= ws_size) {
    bf16* SK  = bufs;
    bf16* qwM = SK + 2 * skel;
    bf16* KS  = qwM + (size_t)2048 * 16384;
    bf16* VT  = KS + (size_t)2048 * 16384;
    stage_k<<<1024 + 2 * 4096 * 2, 256, 0, stream>>>(
        wq, wkv, wp, wqT, wkvT, wpT, qf, qwM, kvf, SK,
        /*b0=*/0, /*nb=*/2, /*skmask=*/1, /*wbP=*/0, /*do_w=*/1);
    convkv_k<<<2048, 256, 0, stream>>>(SK, wdw, wkvT, bkv, KS, VT,
                                       /*wid_base=*/0, /*cnt=*/2048,
                                       /*psw0=*/0, /*skmask=*/1);
    fused_k<<<2048, 256, 0, stream>>>(qwM, wqT, bq, KS, VT, wpT, bp, out,
                                      /*wid_base=*/0, /*nw=*/2048);
    return;
  }

  // ---- mid fallback: per-batch passes with merged stage (1 SK slot) ----
  size_t midelems = welems + skel + (size_t)3 * 1024 * 16384;
  if (midelems * 2 <= ws_size) {
    bf16* SK  = bufs;
    bf16* qwM = SK + skel;
    bf16* KS  = qwM + (size_t)1024 * 16384;
    bf16* VT  = KS + (size_t)1024 * 16384;
    wtrans_k<<<1024, 256, 0, stream>>>(wq, wkv, wp, wqT, wkvT, wpT);
    for (int b = 0; b < 2; ++b) {
      stage_k<<<2 * 4096, 256, 0, stream>>>(
          wq, wkv, wp, wqT, wkvT, wpT, qf, qwM, kvf, SK,
          /*b0=*/b, /*nb=*/1, /*skmask=*/0, /*wbP=*/b * 1024, /*do_w=*/0);
      convkv_k<<<1024, 256, 0, stream>>>(SK, wdw, wkvT, bkv, KS, VT,
                                         b * 1024, 1024, 0, 0);
      fused_k<<<1024, 256, 0, stream>>>(qwM, wqT, bq, KS, VT, wpT, bp, out,
                                        b * 1024, 1024);
    }
    return;
  }

  // ---- deep fallback (tiny workspace): chunked passes ----
  int passes = 4;
  while (passes < 32 &&
         (welems + skel + (size_t)3 * (2048 / passes) * 16384) * 2 > ws_size)
    passes <<= 1;
  int nw = 2048 / passes;
  size_t sz = (size_t)nw * 16384;
  bf16* SK  = bufs;
  bf16* qwM = SK + skel;
  bf16* KS  = qwM + sz;
  bf16* VT  = KS + sz;
  wtrans_k<<<1024, 256, 0, stream>>>(wq, wkv, wp, wqT, wkvT, wpT);
  for (int p = 0; p < passes; ++p) {
    int wbP = p * nw;
    int b0 = wbP >> 10, b1 = (wbP + nw - 1) >> 10;
    for (int b = b0; b <= b1; ++b) {
      int s = wbP > b * 1024 ? wbP : b * 1024;
      int e = (wbP + nw) < (b + 1) * 1024 ? (wbP + nw) : (b + 1) * 1024;
      int cnt = e - s;
      int h0 = ((s & 1023) >> 5) * 8;
      t_winq_k<<<cnt * 4, 256, 0, stream>>>(qf + ((size_t)b << 24), qwM,
                                            h0 * 256, b * 1024 - wbP);
      t_nhwc_k<<<4096, 256, 0, stream>>>(kvf + ((size_t)b << 24), SK);
      convkv_k<<<cnt, 256, 0, stream>>>(SK, wdw, wkvT, bkv, KS, VT,
                                        s, cnt, s - wbP, 0);
    }
    fused_k<<<nw, 256, 0, stream>>>(qwM, wqT, bq, KS, VT, wpT, bp, out, wbP, nw);
  }
}